// Round 3
// baseline (1219.040 us; speedup 1.0000x reference)
//
#include <hip/hip_runtime.h>
#include <math.h>
#include <stdint.h>

#define DD 768
#define NT 256
#define DE 6144

typedef _Float16 half8 __attribute__((ext_vector_type(8)));
typedef float floatx4 __attribute__((ext_vector_type(4)));

__device__ __forceinline__ void async_ld16(const void* g, void* l) {
  __builtin_amdgcn_global_load_lds(
      (const __attribute__((address_space(1))) unsigned int*)g,
      (__attribute__((address_space(3))) unsigned int*)l, 16, 0, 0);
}

// ---------------------------------------------------------------------------
// Prep: WT[d][k] = (f16)W[k][d], stored XOR-swizzled within each 64-f16 chunk:
// 16B-group g of row d lives at group g^(d&7). Lane-contiguous global_load_lds
// then lands a bank-balanced image in LDS.
// ---------------------------------------------------------------------------
__global__ __launch_bounds__(256) void transpose_cvt(
    const float* __restrict__ Wn, const float* __restrict__ Wg,
    _Float16* __restrict__ WnT, _Float16* __restrict__ WgT)
{
  const float* W = blockIdx.z ? Wg : Wn;
  _Float16* WT = blockIdx.z ? WgT : WnT;
  __shared__ float tile[32][33];
  const int tx = threadIdx.x & 31, ty = threadIdx.x >> 5;
  const int d0 = blockIdx.x * 32, k0 = blockIdx.y * 32;
  #pragma unroll
  for (int p = 0; p < 4; ++p)
    tile[ty + p*8][tx] = W[(size_t)(k0 + ty + p*8)*DD + d0 + tx];
  __syncthreads();
  #pragma unroll
  for (int p = 0; p < 4; ++p) {
    const int d = d0 + ty + p*8;
    const int k = k0 + tx;
    const int idx = d*DD + (k & ~63) + ((((k >> 3) & 7) ^ (d & 7)) << 3) + (k & 7);
    WT[idx] = (_Float16)tile[tx][ty + p*8];
  }
}

// ---------------------------------------------------------------------------
// Stage 1: score matrix via f16 MFMA. Block = (i, 128 j, 128 d), K=768.
// A (cmp) built by VALU into swizzled LDS; B staged by global_load_lds (async,
// zero VALU). Epilogue: highway with exact fp32 cmp bypass, contract with Wl.
// ---------------------------------------------------------------------------
__global__ __launch_bounds__(256, 3) void score_mfma(
    const float* __restrict__ L, const float* __restrict__ R,
    const _Float16* __restrict__ WnT, const _Float16* __restrict__ WgT,
    const float* __restrict__ bn, const float* __restrict__ bg,
    const float* __restrict__ Wl, float* __restrict__ S)
{
  const int jbase = blockIdx.x * 128;
  const int dbase = blockIdx.y * 128;
  const int i     = blockIdx.z;
  const int tid   = threadIdx.x;

  __shared__ _Float16 As [128*64];   // [row][k] swizzled, 16 KB
  __shared__ _Float16 Bns[128*64];
  __shared__ _Float16 Bgs[128*64];

  floatx4 accn[4][4] = {};
  floatx4 accg[4][4] = {};

  const int kg = tid & 7;     // 16B group within 64-f16 chunk
  const int rl = tid >> 3;    // 0..31 base row for A build

  const int lane = tid & 63;
  const int wid  = tid >> 6;
  const int wj = (wid & 1) * 64;
  const int wd = (wid >> 1) * 64;
  const int m = lane & 15;
  const int q = lane >> 4;
  const int gq8 = ((q ^ (m & 7)) << 3);  // swizzled fragment k-offset base (f16)

  // DMA lane mapping: 8 rows per inst, lane>>3 = row-in-group, lane&7 = seg
  const int drow = lane >> 3;
  const int dseg = lane & 7;

  int aoff[4], boff[4];
  #pragma unroll
  for (int t4 = 0; t4 < 4; ++t4) {
    aoff[t4] = (wj + t4*16 + m) * 64;
    boff[t4] = (wd + t4*16 + m) * 64;
  }

  for (int k0 = 0; k0 < DD; k0 += 64) {
    // ---- B tiles via async global->LDS (swizzled image pre-baked in WnT/WgT)
    #pragma unroll
    for (int t = 0; t < 4; ++t) {
      const int row = wid*32 + t*8 + drow;
      async_ld16(&WnT[(size_t)(dbase + row)*DD + k0 + dseg*8],
                 &Bns[(wid*32 + t*8)*64]);
      async_ld16(&WgT[(size_t)(dbase + row)*DD + k0 + dseg*8],
                 &Bgs[(wid*32 + t*8)*64]);
    }
    // ---- A tile: |L[i,k]-R[j,k]| fp32 -> fp16, swizzled store
    float l8[8];
    *(float4*)&l8[0] = *(const float4*)&L[i*DD + k0 + kg*8];
    *(float4*)&l8[4] = *(const float4*)&L[i*DD + k0 + kg*8 + 4];
    #pragma unroll
    for (int rep = 0; rep < 4; ++rep) {
      const int row = rl + rep*32;
      float rv[8];
      const float* Rrow = &R[(size_t)(jbase + row)*DD + k0 + kg*8];
      *(float4*)&rv[0] = *(const float4*)&Rrow[0];
      *(float4*)&rv[4] = *(const float4*)&Rrow[4];
      half8 h;
      #pragma unroll
      for (int e = 0; e < 8; ++e) h[e] = (_Float16)fabsf(l8[e] - rv[e]);
      *(half8*)&As[row*64 + ((kg ^ (row & 7)) << 3)] = h;
    }
    __syncthreads();
    // ---- MFMA: wave = 64j x 64d, 4x4 16x16 tiles, two matrices
    #pragma unroll
    for (int kk = 0; kk < 64; kk += 32) {
      const int ko = kk ^ gq8;   // (kk>>3 ^ q ^ (m&7))<<3, kk multiple of 32
      half8 af[4], bfn[4], bfg[4];
      #pragma unroll
      for (int t4 = 0; t4 < 4; ++t4) af[t4] = *(const half8*)&As[aoff[t4] + ko];
      #pragma unroll
      for (int t4 = 0; t4 < 4; ++t4) {
        bfn[t4] = *(const half8*)&Bns[boff[t4] + ko];
        bfg[t4] = *(const half8*)&Bgs[boff[t4] + ko];
      }
      #pragma unroll
      for (int tj = 0; tj < 4; ++tj)
        #pragma unroll
        for (int td = 0; td < 4; ++td) {
          accn[tj][td] = __builtin_amdgcn_mfma_f32_16x16x32_f16(
              af[tj], bfn[td], accn[tj][td], 0, 0, 0);
          accg[tj][td] = __builtin_amdgcn_mfma_f32_16x16x32_f16(
              af[tj], bfg[td], accg[tj][td], 0, 0, 0);
        }
    }
    __syncthreads();
  }

  // ---- epilogue: highway + Wl contraction; C layout col=lane&15, row=q*4+r
  float bnv[4], bgv[4], wlv[4], lv[4];
  int dv[4];
  #pragma unroll
  for (int td = 0; td < 4; ++td) {
    const int d = dbase + wd + td*16 + m;
    dv[td] = d; bnv[td] = bn[d]; bgv[td] = bg[d]; wlv[td] = Wl[d];
    lv[td] = L[i*DD + d];
  }
  const int jb = jbase + wj;
  #pragma unroll
  for (int tj = 0; tj < 4; ++tj) {
    #pragma unroll
    for (int r = 0; r < 4; ++r) {
      const int j = jb + tj*16 + q*4 + r;
      float sc = 0.f;
      #pragma unroll
      for (int td = 0; td < 4; ++td) {
        const float nv = accn[tj][td][r] + bnv[td];
        const float gp = accg[tj][td][r] + bgv[td];
        const float g  = 1.f / (1.f + __expf(-gp));
        const float c  = fabsf(lv[td] - R[(size_t)j*DD + dv[td]]);
        sc += (fmaxf(nv, 0.f)*g + (1.f - g)*c) * wlv[td];
      }
      sc += __shfl_xor(sc, 1, 16);
      sc += __shfl_xor(sc, 2, 16);
      sc += __shfl_xor(sc, 4, 16);
      sc += __shfl_xor(sc, 8, 16);
      if (m == 0) atomicAdd(&S[i*NT + j], sc);
    }
  }
}

// ---------------------------------------------------------------------------
// Stage 2: argmax over rows (left) and cols (right), first-index tie-break.
// ---------------------------------------------------------------------------
__global__ __launch_bounds__(256) void argmax_kernel(const float* __restrict__ S,
    int* __restrict__ idxL, int* __restrict__ idxR)
{
  int b = blockIdx.x;
  int t = threadIdx.x;
  float v = (b < NT) ? S[b*NT + t] : S[t*NT + (b - NT)];
  int idx = t;
  #pragma unroll
  for (int mm = 1; mm < 64; mm <<= 1) {
    float ov = __shfl_xor(v, mm, 64);
    int   oi = __shfl_xor(idx, mm, 64);
    if (ov > v || (ov == v && oi < idx)) { v = ov; idx = oi; }
  }
  __shared__ float sv[4]; __shared__ int si[4];
  if ((t & 63) == 0) { sv[t>>6] = v; si[t>>6] = idx; }
  __syncthreads();
  if (t == 0) {
    #pragma unroll
    for (int w = 1; w < 4; ++w)
      if (sv[w] > v || (sv[w] == v && si[w] < idx)) { v = sv[w]; idx = si[w]; }
    if (b < NT) idxL[b] = idx; else idxR[b - NT] = idx;
  }
}

// ---------------------------------------------------------------------------
// Stage 3a: per-token attribute scores + segment softmax weights (2 blocks).
// ---------------------------------------------------------------------------
__global__ __launch_bounds__(256) void attr_score(
    const float* __restrict__ Lemb, const float* __restrict__ Remb,
    const float* __restrict__ AEl, const float* __restrict__ AEr,
    const int* __restrict__ lensL, const int* __restrict__ lensR,
    float* __restrict__ wS, int* __restrict__ segA)
{
  const int side = blockIdx.x;
  const float* tok = side ? Remb : Lemb;
  const float* AE  = side ? AEr  : AEl;
  const int* lens  = side ? lensR : lensL;
  const int t = threadIdx.x;
  const int c0 = lens[0], c1 = c0 + lens[1], c2 = c1 + lens[2];
  const int seg = (t < c0) ? 0 : (t < c1) ? 1 : (t < c2) ? 2 : 3;
  float s = 0.f;
  const float4* tr = (const float4*)&tok[(size_t)t*DD];
  const float4* ar = (const float4*)&AE[(size_t)seg*DD];
  for (int k = 0; k < DD/4; ++k) {
    float4 a = tr[k], b = ar[k];
    s += a.x*b.x + a.y*b.y + a.z*b.z + a.w*b.w;
  }
  __shared__ float scS[NT]; __shared__ int segS[NT];
  __shared__ float mS[4], zS[4];
  scS[t] = s; segS[t] = seg;
  __syncthreads();
  if (t < 4) {
    float m = -INFINITY;
    for (int u = 0; u < NT; ++u) if (segS[u] == t) m = fmaxf(m, scS[u]);
    mS[t] = m;
    float z = 0.f;
    for (int u = 0; u < NT; ++u) if (segS[u] == t) z += __expf(scS[u] - m);
    zS[t] = z;
  }
  __syncthreads();
  wS[side*NT + t] = __expf(s - mS[seg]) / zS[seg];
  segA[side*NT + t] = seg;
}

// ---------------------------------------------------------------------------
// Stage 3b: weighted segment reduction of cmp rows, d-parallel (2x12 blocks).
// ---------------------------------------------------------------------------
__global__ __launch_bounds__(256) void attr_reduce(
    const float* __restrict__ Lemb, const float* __restrict__ Remb,
    const int* __restrict__ lensL, const int* __restrict__ lensR,
    const int* __restrict__ idxL, const int* __restrict__ idxR,
    const float* __restrict__ wS, const int* __restrict__ segA,
    const float* __restrict__ empty, float* __restrict__ x)
{
  const int side = blockIdx.x;
  const float* tok = side ? Remb : Lemb;
  const float* oth = side ? Lemb : Remb;
  const int* lens  = side ? lensR : lensL;
  const int* idx   = side ? idxR  : idxL;
  const float* w   = wS + side*NT;
  const int* sg    = segA + side*NT;
  float* xo = x + side*4*DD;
  const int t = threadIdx.x;
  const int dl = t & 63, uq = t >> 6;
  const int d = blockIdx.y*64 + dl;
  float a0 = 0.f, a1 = 0.f, a2 = 0.f, a3 = 0.f;
  for (int u = uq*64; u < uq*64 + 64; ++u) {
    const float c = fabsf(tok[(size_t)u*DD + d] - oth[(size_t)idx[u]*DD + d]);
    const float wc = w[u] * c;
    const int s = sg[u];
    a0 += (s == 0) ? wc : 0.f;
    a1 += (s == 1) ? wc : 0.f;
    a2 += (s == 2) ? wc : 0.f;
    a3 += (s == 3) ? wc : 0.f;
  }
  __shared__ float red[4][4][64];
  red[uq][0][dl] = a0; red[uq][1][dl] = a1;
  red[uq][2][dl] = a2; red[uq][3][dl] = a3;
  __syncthreads();
  if (uq == 0) {
    #pragma unroll
    for (int s = 0; s < 4; ++s) {
      float v = red[0][s][dl] + red[1][s][dl] + red[2][s][dl] + red[3][s][dl];
      xo[s*DD + d] = (lens[s] > 0) ? v : empty[d];
    }
  }
}

// ---------------------------------------------------------------------------
// Stage 4a: entity matvecs, float4 streaming, k-split into partials (no
// atomics). 302 MB fp32 weights -> HBM-bound. grid (6 dcol-blocks, 64 k-blocks)
// ---------------------------------------------------------------------------
__global__ __launch_bounds__(256) void ent_matvec4(
    const float* __restrict__ x,
    const float* __restrict__ Wn, const float* __restrict__ Wg,
    float* __restrict__ pn, float* __restrict__ pg)
{
  __shared__ float xs[96];
  const int db = blockIdx.x;
  const int kb = blockIdx.y;
  const int tid = threadIdx.x;
  if (tid < 96) xs[tid] = x[kb*96 + tid];
  __syncthreads();
  const int col = db*1024 + tid*4;
  float4 an = {0.f,0.f,0.f,0.f}, ag = {0.f,0.f,0.f,0.f};
  const size_t base = (size_t)kb*96*DE + col;
  #pragma unroll 8
  for (int kk = 0; kk < 96; ++kk) {
    const float xv = xs[kk];
    float4 wn = *(const float4*)&Wn[base + (size_t)kk*DE];
    float4 wg = *(const float4*)&Wg[base + (size_t)kk*DE];
    an.x = fmaf(xv, wn.x, an.x); an.y = fmaf(xv, wn.y, an.y);
    an.z = fmaf(xv, wn.z, an.z); an.w = fmaf(xv, wn.w, an.w);
    ag.x = fmaf(xv, wg.x, ag.x); ag.y = fmaf(xv, wg.y, ag.y);
    ag.z = fmaf(xv, wg.z, ag.z); ag.w = fmaf(xv, wg.w, ag.w);
  }
  *(float4*)&pn[(size_t)kb*DE + col] = an;
  *(float4*)&pg[(size_t)kb*DE + col] = ag;
}

__global__ __launch_bounds__(256) void ent_reduce(
    const float* __restrict__ pn, const float* __restrict__ pg,
    float* __restrict__ yn, float* __restrict__ yg)
{
  const int o = blockIdx.x*256 + threadIdx.x;   // 24 blocks -> 6144
  float sn = 0.f, sg = 0.f;
  for (int kb = 0; kb < 64; ++kb) {
    sn += pn[(size_t)kb*DE + o];
    sg += pg[(size_t)kb*DE + o];
  }
  yn[o] = sn; yg[o] = sg;
}

// ---------------------------------------------------------------------------
// Stage 4b: entity highway + logits + softmax -> out[2].
// ---------------------------------------------------------------------------
__global__ __launch_bounds__(256) void final_kernel(
    const float* __restrict__ x, const float* __restrict__ yn,
    const float* __restrict__ yg, const float* __restrict__ bn,
    const float* __restrict__ bg, const float* __restrict__ Wl,
    const float* __restrict__ bl, float* __restrict__ out)
{
  const int tid = threadIdx.x;
  float a0 = 0.f, a1 = 0.f;
  for (int p = 0; p < DE/256; ++p) {
    int d = p*256 + tid;
    float n  = yn[d] + bn[d];
    float gp = yg[d] + bg[d];
    float h  = fmaxf(n, 0.f);
    float g  = 1.f / (1.f + __expf(-gp));
    float hw = h*g + (1.f - g)*x[d];
    a0 += hw * Wl[d*2 + 0];
    a1 += hw * Wl[d*2 + 1];
  }
  #pragma unroll
  for (int mm = 1; mm < 64; mm <<= 1) {
    a0 += __shfl_xor(a0, mm, 64);
    a1 += __shfl_xor(a1, mm, 64);
  }
  __shared__ float s0[4], s1[4];
  if ((tid & 63) == 0) { s0[tid>>6] = a0; s1[tid>>6] = a1; }
  __syncthreads();
  if (tid == 0) {
    for (int w = 1; w < 4; ++w) { a0 += s0[w]; a1 += s1[w]; }
    float l0 = a0 + bl[0], l1 = a1 + bl[1];
    float m = fmaxf(l0, l1);
    float e0 = __expf(l0 - m), e1 = __expf(l1 - m);
    out[0] = e0 / (e0 + e1);
    out[1] = e1 / (e0 + e1);
  }
}

// ---------------------------------------------------------------------------
extern "C" void kernel_launch(void* const* d_in, const int* in_sizes, int n_in,
                              void* d_out, int out_size, void* d_ws, size_t ws_size,
                              hipStream_t stream) {
  const float* Lemb   = (const float*)d_in[0];
  const float* Remb   = (const float*)d_in[1];
  const float* Wn_tok = (const float*)d_in[2];
  const float* bn_tok = (const float*)d_in[3];
  const float* Wg_tok = (const float*)d_in[4];
  const float* bg_tok = (const float*)d_in[5];
  const float* Wl_tok = (const float*)d_in[6];
  // d_in[7] = b_lin_tok: constant shift, argmax-invariant -> unused
  const float* AEl    = (const float*)d_in[8];
  const float* AEr    = (const float*)d_in[9];
  const float* Wn_ent = (const float*)d_in[10];
  const float* bn_ent = (const float*)d_in[11];
  const float* Wg_ent = (const float*)d_in[12];
  const float* bg_ent = (const float*)d_in[13];
  const float* Wl_ent = (const float*)d_in[14];
  const float* bl_ent = (const float*)d_in[15];
  const float* empty  = (const float*)d_in[16];
  const int*   lensL  = (const int*)d_in[17];
  const int*   lensR  = (const int*)d_in[18];

  char* ws = (char*)d_ws;
  float* S    = (float*)(ws + 0);         // 65536 f
  int*  idxL  = (int*)  (ws + 262144);    // 256
  int*  idxR  = (int*)  (ws + 263168);    // 256
  float* x    = (float*)(ws + 264192);    // 6144 f
  float* yn   = (float*)(ws + 288768);    // 6144 f
  float* yg   = (float*)(ws + 313344);    // 6144 f
  float* wSm  = (float*)(ws + 337920);    // 512 f
  int*  segA  = (int*)  (ws + 339968);    // 512
  _Float16* WnT = (_Float16*)(ws + 342016);   // 768*768 f16 (swizzled)
  _Float16* WgT = (_Float16*)(ws + 1521664);  // 768*768 f16 (swizzled)
  float* pn   = (float*)(ws + 2701312);   // 64*6144 f
  float* pg   = (float*)(ws + 4274176);   // 64*6144 f

  hipMemsetAsync(S, 0, (size_t)NT*NT*sizeof(float), stream);

  transpose_cvt<<<dim3(24, 24, 2), 256, 0, stream>>>(Wn_tok, Wg_tok, WnT, WgT);
  score_mfma<<<dim3(2, 6, NT), 256, 0, stream>>>(
      Lemb, Remb, WnT, WgT, bn_tok, bg_tok, Wl_tok, S);
  argmax_kernel<<<512, 256, 0, stream>>>(S, idxL, idxR);
  attr_score<<<2, 256, 0, stream>>>(Lemb, Remb, AEl, AEr, lensL, lensR, wSm, segA);
  attr_reduce<<<dim3(2, 12), 256, 0, stream>>>(
      Lemb, Remb, lensL, lensR, idxL, idxR, wSm, segA, empty, x);
  ent_matvec4<<<dim3(6, 64), 256, 0, stream>>>(x, Wn_ent, Wg_ent, pn, pg);
  ent_reduce<<<24, 256, 0, stream>>>(pn, pg, yn, yg);
  final_kernel<<<1, 256, 0, stream>>>(
      x, yn, yg, bn_ent, bg_ent, Wl_ent, bl_ent, (float*)d_out);
}

// Round 4
// 667.085 us; speedup vs baseline: 1.8274x; 1.8274x over previous
//
#include <hip/hip_runtime.h>
#include <math.h>
#include <stdint.h>

#define DD 768
#define NT 256
#define DE 6144

typedef _Float16 half8 __attribute__((ext_vector_type(8)));
typedef float floatx4 __attribute__((ext_vector_type(4)));

__device__ __forceinline__ void async_ld16(const void* g, void* l) {
  __builtin_amdgcn_global_load_lds(
      (const __attribute__((address_space(1))) unsigned int*)g,
      (__attribute__((address_space(3))) unsigned int*)l, 16, 0, 0);
}

// ---------------------------------------------------------------------------
// Prep: WT[d][k] = (f16)W[k][d], stored XOR-swizzled within each 64-f16 chunk:
// 16B-group g of row d lives at group g^(d&7). Lane-contiguous global_load_lds
// then lands a bank-balanced image in LDS.
// ---------------------------------------------------------------------------
__global__ __launch_bounds__(256) void transpose_cvt(
    const float* __restrict__ Wn, const float* __restrict__ Wg,
    _Float16* __restrict__ WnT, _Float16* __restrict__ WgT)
{
  const float* W = blockIdx.z ? Wg : Wn;
  _Float16* WT = blockIdx.z ? WgT : WnT;
  __shared__ float tile[32][33];
  const int tx = threadIdx.x & 31, ty = threadIdx.x >> 5;
  const int d0 = blockIdx.x * 32, k0 = blockIdx.y * 32;
  #pragma unroll
  for (int p = 0; p < 4; ++p)
    tile[ty + p*8][tx] = W[(size_t)(k0 + ty + p*8)*DD + d0 + tx];
  __syncthreads();
  #pragma unroll
  for (int p = 0; p < 4; ++p) {
    const int d = d0 + ty + p*8;
    const int k = k0 + tx;
    const int idx = d*DD + (k & ~63) + ((((k >> 3) & 7) ^ (d & 7)) << 3) + (k & 7);
    WT[idx] = (_Float16)tile[tx][ty + p*8];
  }
}

// ---------------------------------------------------------------------------
// Stage 1: score matrix via f16 MFMA. Block = (i, 128 j, 128 d), K=768.
// A (cmp) built by VALU into swizzled LDS; B staged by global_load_lds (async,
// zero VALU). Epilogue: highway with exact fp32 cmp bypass, contract with Wl.
// NOTE launch_bounds must stay (256,2): acc tile needs ~128 regs; (256,3)
// caps the unified file at ~170 and spills accumulators (r3: 2.8 GB scratch
// traffic, 3x slowdown).
// ---------------------------------------------------------------------------
__global__ __launch_bounds__(256, 2) void score_mfma(
    const float* __restrict__ L, const float* __restrict__ R,
    const _Float16* __restrict__ WnT, const _Float16* __restrict__ WgT,
    const float* __restrict__ bn, const float* __restrict__ bg,
    const float* __restrict__ Wl, float* __restrict__ S)
{
  const int jbase = blockIdx.x * 128;
  const int dbase = blockIdx.y * 128;
  const int i     = blockIdx.z;
  const int tid   = threadIdx.x;

  __shared__ _Float16 As [128*64];   // [row][k] swizzled, 16 KB
  __shared__ _Float16 Bns[128*64];
  __shared__ _Float16 Bgs[128*64];

  floatx4 accn[4][4] = {};
  floatx4 accg[4][4] = {};

  const int kg = tid & 7;     // 16B group within 64-f16 chunk
  const int rl = tid >> 3;    // 0..31 base row for A build

  const int lane = tid & 63;
  const int wid  = tid >> 6;
  const int wj = (wid & 1) * 64;
  const int wd = (wid >> 1) * 64;
  const int m = lane & 15;
  const int q = lane >> 4;
  const int gq8 = ((q ^ (m & 7)) << 3);  // swizzled fragment k-offset base (f16)

  // DMA lane mapping: 8 rows per inst, lane>>3 = row-in-group, lane&7 = seg
  const int drow = lane >> 3;
  const int dseg = lane & 7;

  int aoff[4], boff[4];
  #pragma unroll
  for (int t4 = 0; t4 < 4; ++t4) {
    aoff[t4] = (wj + t4*16 + m) * 64;
    boff[t4] = (wd + t4*16 + m) * 64;
  }

  for (int k0 = 0; k0 < DD; k0 += 64) {
    // ---- B tiles via async global->LDS (swizzled image pre-baked in WnT/WgT)
    #pragma unroll
    for (int t = 0; t < 4; ++t) {
      const int row = wid*32 + t*8 + drow;
      async_ld16(&WnT[(size_t)(dbase + row)*DD + k0 + dseg*8],
                 &Bns[(wid*32 + t*8)*64]);
      async_ld16(&WgT[(size_t)(dbase + row)*DD + k0 + dseg*8],
                 &Bgs[(wid*32 + t*8)*64]);
    }
    // ---- A tile: |L[i,k]-R[j,k]| fp32 -> fp16, swizzled store
    float l8[8];
    *(float4*)&l8[0] = *(const float4*)&L[i*DD + k0 + kg*8];
    *(float4*)&l8[4] = *(const float4*)&L[i*DD + k0 + kg*8 + 4];
    #pragma unroll
    for (int rep = 0; rep < 4; ++rep) {
      const int row = rl + rep*32;
      float rv[8];
      const float* Rrow = &R[(size_t)(jbase + row)*DD + k0 + kg*8];
      *(float4*)&rv[0] = *(const float4*)&Rrow[0];
      *(float4*)&rv[4] = *(const float4*)&Rrow[4];
      half8 h;
      #pragma unroll
      for (int e = 0; e < 8; ++e) h[e] = (_Float16)fabsf(l8[e] - rv[e]);
      *(half8*)&As[row*64 + ((kg ^ (row & 7)) << 3)] = h;
    }
    __syncthreads();
    // ---- MFMA: wave = 64j x 64d, 4x4 16x16 tiles, two matrices
    #pragma unroll
    for (int kk = 0; kk < 64; kk += 32) {
      const int ko = kk ^ gq8;   // (kk>>3 ^ q ^ (m&7))<<3, kk multiple of 32
      half8 af[4], bfn[4], bfg[4];
      #pragma unroll
      for (int t4 = 0; t4 < 4; ++t4) af[t4] = *(const half8*)&As[aoff[t4] + ko];
      #pragma unroll
      for (int t4 = 0; t4 < 4; ++t4) {
        bfn[t4] = *(const half8*)&Bns[boff[t4] + ko];
        bfg[t4] = *(const half8*)&Bgs[boff[t4] + ko];
      }
      #pragma unroll
      for (int tj = 0; tj < 4; ++tj)
        #pragma unroll
        for (int td = 0; td < 4; ++td) {
          accn[tj][td] = __builtin_amdgcn_mfma_f32_16x16x32_f16(
              af[tj], bfn[td], accn[tj][td], 0, 0, 0);
          accg[tj][td] = __builtin_amdgcn_mfma_f32_16x16x32_f16(
              af[tj], bfg[td], accg[tj][td], 0, 0, 0);
        }
    }
    __syncthreads();
  }

  // ---- epilogue: highway + Wl contraction; C layout col=lane&15, row=q*4+r
  float bnv[4], bgv[4], wlv[4], lv[4];
  int dv[4];
  #pragma unroll
  for (int td = 0; td < 4; ++td) {
    const int d = dbase + wd + td*16 + m;
    dv[td] = d; bnv[td] = bn[d]; bgv[td] = bg[d]; wlv[td] = Wl[d];
    lv[td] = L[i*DD + d];
  }
  const int jb = jbase + wj;
  #pragma unroll
  for (int tj = 0; tj < 4; ++tj) {
    #pragma unroll
    for (int r = 0; r < 4; ++r) {
      const int j = jb + tj*16 + q*4 + r;
      float sc = 0.f;
      #pragma unroll
      for (int td = 0; td < 4; ++td) {
        const float nv = accn[tj][td][r] + bnv[td];
        const float gp = accg[tj][td][r] + bgv[td];
        const float g  = 1.f / (1.f + __expf(-gp));
        const float c  = fabsf(lv[td] - R[(size_t)j*DD + dv[td]]);
        sc += (fmaxf(nv, 0.f)*g + (1.f - g)*c) * wlv[td];
      }
      sc += __shfl_xor(sc, 1, 16);
      sc += __shfl_xor(sc, 2, 16);
      sc += __shfl_xor(sc, 4, 16);
      sc += __shfl_xor(sc, 8, 16);
      if (m == 0) atomicAdd(&S[i*NT + j], sc);
    }
  }
}

// ---------------------------------------------------------------------------
// Stage 2: argmax over rows (left) and cols (right), first-index tie-break.
// ---------------------------------------------------------------------------
__global__ __launch_bounds__(256) void argmax_kernel(const float* __restrict__ S,
    int* __restrict__ idxL, int* __restrict__ idxR)
{
  int b = blockIdx.x;
  int t = threadIdx.x;
  float v = (b < NT) ? S[b*NT + t] : S[t*NT + (b - NT)];
  int idx = t;
  #pragma unroll
  for (int mm = 1; mm < 64; mm <<= 1) {
    float ov = __shfl_xor(v, mm, 64);
    int   oi = __shfl_xor(idx, mm, 64);
    if (ov > v || (ov == v && oi < idx)) { v = ov; idx = oi; }
  }
  __shared__ float sv[4]; __shared__ int si[4];
  if ((t & 63) == 0) { sv[t>>6] = v; si[t>>6] = idx; }
  __syncthreads();
  if (t == 0) {
    #pragma unroll
    for (int w = 1; w < 4; ++w)
      if (sv[w] > v || (sv[w] == v && si[w] < idx)) { v = sv[w]; idx = si[w]; }
    if (b < NT) idxL[b] = idx; else idxR[b - NT] = idx;
  }
}

// ---------------------------------------------------------------------------
// Stage 3a: per-token attribute scores + segment softmax weights (2 blocks).
// ---------------------------------------------------------------------------
__global__ __launch_bounds__(256) void attr_score(
    const float* __restrict__ Lemb, const float* __restrict__ Remb,
    const float* __restrict__ AEl, const float* __restrict__ AEr,
    const int* __restrict__ lensL, const int* __restrict__ lensR,
    float* __restrict__ wS, int* __restrict__ segA)
{
  const int side = blockIdx.x;
  const float* tok = side ? Remb : Lemb;
  const float* AE  = side ? AEr  : AEl;
  const int* lens  = side ? lensR : lensL;
  const int t = threadIdx.x;
  const int c0 = lens[0], c1 = c0 + lens[1], c2 = c1 + lens[2];
  const int seg = (t < c0) ? 0 : (t < c1) ? 1 : (t < c2) ? 2 : 3;
  float s = 0.f;
  const float4* tr = (const float4*)&tok[(size_t)t*DD];
  const float4* ar = (const float4*)&AE[(size_t)seg*DD];
  for (int k = 0; k < DD/4; ++k) {
    float4 a = tr[k], b = ar[k];
    s += a.x*b.x + a.y*b.y + a.z*b.z + a.w*b.w;
  }
  __shared__ float scS[NT]; __shared__ int segS[NT];
  __shared__ float mS[4], zS[4];
  scS[t] = s; segS[t] = seg;
  __syncthreads();
  if (t < 4) {
    float m = -INFINITY;
    for (int u = 0; u < NT; ++u) if (segS[u] == t) m = fmaxf(m, scS[u]);
    mS[t] = m;
    float z = 0.f;
    for (int u = 0; u < NT; ++u) if (segS[u] == t) z += __expf(scS[u] - m);
    zS[t] = z;
  }
  __syncthreads();
  wS[side*NT + t] = __expf(s - mS[seg]) / zS[seg];
  segA[side*NT + t] = seg;
}

// ---------------------------------------------------------------------------
// Stage 3b: weighted segment reduction of cmp rows, d-parallel (2x12 blocks).
// ---------------------------------------------------------------------------
__global__ __launch_bounds__(256) void attr_reduce(
    const float* __restrict__ Lemb, const float* __restrict__ Remb,
    const int* __restrict__ lensL, const int* __restrict__ lensR,
    const int* __restrict__ idxL, const int* __restrict__ idxR,
    const float* __restrict__ wS, const int* __restrict__ segA,
    const float* __restrict__ empty, float* __restrict__ x)
{
  const int side = blockIdx.x;
  const float* tok = side ? Remb : Lemb;
  const float* oth = side ? Lemb : Remb;
  const int* lens  = side ? lensR : lensL;
  const int* idx   = side ? idxR  : idxL;
  const float* w   = wS + side*NT;
  const int* sg    = segA + side*NT;
  float* xo = x + side*4*DD;
  const int t = threadIdx.x;
  const int dl = t & 63, uq = t >> 6;
  const int d = blockIdx.y*64 + dl;
  float a0 = 0.f, a1 = 0.f, a2 = 0.f, a3 = 0.f;
  for (int u = uq*64; u < uq*64 + 64; ++u) {
    const float c = fabsf(tok[(size_t)u*DD + d] - oth[(size_t)idx[u]*DD + d]);
    const float wc = w[u] * c;
    const int s = sg[u];
    a0 += (s == 0) ? wc : 0.f;
    a1 += (s == 1) ? wc : 0.f;
    a2 += (s == 2) ? wc : 0.f;
    a3 += (s == 3) ? wc : 0.f;
  }
  __shared__ float red[4][4][64];
  red[uq][0][dl] = a0; red[uq][1][dl] = a1;
  red[uq][2][dl] = a2; red[uq][3][dl] = a3;
  __syncthreads();
  if (uq == 0) {
    #pragma unroll
    for (int s = 0; s < 4; ++s) {
      float v = red[0][s][dl] + red[1][s][dl] + red[2][s][dl] + red[3][s][dl];
      xo[s*DD + d] = (lens[s] > 0) ? v : empty[d];
    }
  }
}

// ---------------------------------------------------------------------------
// Stage 4a: entity matvecs, float4 streaming, k-split into partials (no
// atomics). z picks the matrix (Wn/Wg). grid (6, 64, 2) = 768 blocks.
// ---------------------------------------------------------------------------
__global__ __launch_bounds__(256) void ent_matvec4(
    const float* __restrict__ x,
    const float* __restrict__ Wn, const float* __restrict__ Wg,
    float* __restrict__ pn, float* __restrict__ pg)
{
  const float* W = blockIdx.z ? Wg : Wn;
  float* p = blockIdx.z ? pg : pn;
  __shared__ float xs[96];
  const int db = blockIdx.x;
  const int kb = blockIdx.y;
  const int tid = threadIdx.x;
  if (tid < 96) xs[tid] = x[kb*96 + tid];
  __syncthreads();
  const int col = db*1024 + tid*4;
  float4 a = {0.f,0.f,0.f,0.f};
  const size_t base = (size_t)kb*96*DE + col;
  #pragma unroll 8
  for (int kk = 0; kk < 96; ++kk) {
    const float xv = xs[kk];
    float4 w = *(const float4*)&W[base + (size_t)kk*DE];
    a.x = fmaf(xv, w.x, a.x); a.y = fmaf(xv, w.y, a.y);
    a.z = fmaf(xv, w.z, a.z); a.w = fmaf(xv, w.w, a.w);
  }
  *(float4*)&p[(size_t)kb*DE + col] = a;
}

__global__ __launch_bounds__(256) void ent_reduce(
    const float* __restrict__ pn, const float* __restrict__ pg,
    float* __restrict__ yn, float* __restrict__ yg)
{
  const int o = blockIdx.x*256 + threadIdx.x;   // 24 blocks -> 6144
  float sn = 0.f, sg = 0.f;
  for (int kb = 0; kb < 64; ++kb) {
    sn += pn[(size_t)kb*DE + o];
    sg += pg[(size_t)kb*DE + o];
  }
  yn[o] = sn; yg[o] = sg;
}

// ---------------------------------------------------------------------------
// Stage 4b: entity highway + logits + softmax -> out[2].
// ---------------------------------------------------------------------------
__global__ __launch_bounds__(256) void final_kernel(
    const float* __restrict__ x, const float* __restrict__ yn,
    const float* __restrict__ yg, const float* __restrict__ bn,
    const float* __restrict__ bg, const float* __restrict__ Wl,
    const float* __restrict__ bl, float* __restrict__ out)
{
  const int tid = threadIdx.x;
  float a0 = 0.f, a1 = 0.f;
  for (int p = 0; p < DE/256; ++p) {
    int d = p*256 + tid;
    float n  = yn[d] + bn[d];
    float gp = yg[d] + bg[d];
    float h  = fmaxf(n, 0.f);
    float g  = 1.f / (1.f + __expf(-gp));
    float hw = h*g + (1.f - g)*x[d];
    a0 += hw * Wl[d*2 + 0];
    a1 += hw * Wl[d*2 + 1];
  }
  #pragma unroll
  for (int mm = 1; mm < 64; mm <<= 1) {
    a0 += __shfl_xor(a0, mm, 64);
    a1 += __shfl_xor(a1, mm, 64);
  }
  __shared__ float s0[4], s1[4];
  if ((tid & 63) == 0) { s0[tid>>6] = a0; s1[tid>>6] = a1; }
  __syncthreads();
  if (tid == 0) {
    for (int w = 1; w < 4; ++w) { a0 += s0[w]; a1 += s1[w]; }
    float l0 = a0 + bl[0], l1 = a1 + bl[1];
    float m = fmaxf(l0, l1);
    float e0 = __expf(l0 - m), e1 = __expf(l1 - m);
    out[0] = e0 / (e0 + e1);
    out[1] = e1 / (e0 + e1);
  }
}

// ---------------------------------------------------------------------------
extern "C" void kernel_launch(void* const* d_in, const int* in_sizes, int n_in,
                              void* d_out, int out_size, void* d_ws, size_t ws_size,
                              hipStream_t stream) {
  const float* Lemb   = (const float*)d_in[0];
  const float* Remb   = (const float*)d_in[1];
  const float* Wn_tok = (const float*)d_in[2];
  const float* bn_tok = (const float*)d_in[3];
  const float* Wg_tok = (const float*)d_in[4];
  const float* bg_tok = (const float*)d_in[5];
  const float* Wl_tok = (const float*)d_in[6];
  // d_in[7] = b_lin_tok: constant shift, argmax-invariant -> unused
  const float* AEl    = (const float*)d_in[8];
  const float* AEr    = (const float*)d_in[9];
  const float* Wn_ent = (const float*)d_in[10];
  const float* bn_ent = (const float*)d_in[11];
  const float* Wg_ent = (const float*)d_in[12];
  const float* bg_ent = (const float*)d_in[13];
  const float* Wl_ent = (const float*)d_in[14];
  const float* bl_ent = (const float*)d_in[15];
  const float* empty  = (const float*)d_in[16];
  const int*   lensL  = (const int*)d_in[17];
  const int*   lensR  = (const int*)d_in[18];

  char* ws = (char*)d_ws;
  float* S    = (float*)(ws + 0);         // 65536 f
  int*  idxL  = (int*)  (ws + 262144);    // 256
  int*  idxR  = (int*)  (ws + 263168);    // 256
  float* x    = (float*)(ws + 264192);    // 6144 f
  float* yn   = (float*)(ws + 288768);    // 6144 f
  float* yg   = (float*)(ws + 313344);    // 6144 f
  float* wSm  = (float*)(ws + 337920);    // 512 f
  int*  segA  = (int*)  (ws + 339968);    // 512
  _Float16* WnT = (_Float16*)(ws + 342016);   // 768*768 f16 (swizzled)
  _Float16* WgT = (_Float16*)(ws + 1521664);  // 768*768 f16 (swizzled)
  float* pn   = (float*)(ws + 2701312);   // 64*6144 f
  float* pg   = (float*)(ws + 4274176);   // 64*6144 f

  hipMemsetAsync(S, 0, (size_t)NT*NT*sizeof(float), stream);

  transpose_cvt<<<dim3(24, 24, 2), 256, 0, stream>>>(Wn_tok, Wg_tok, WnT, WgT);
  score_mfma<<<dim3(2, 6, NT), 256, 0, stream>>>(
      Lemb, Remb, WnT, WgT, bn_tok, bg_tok, Wl_tok, S);
  argmax_kernel<<<512, 256, 0, stream>>>(S, idxL, idxR);
  attr_score<<<2, 256, 0, stream>>>(Lemb, Remb, AEl, AEr, lensL, lensR, wSm, segA);
  attr_reduce<<<dim3(2, 12), 256, 0, stream>>>(
      Lemb, Remb, lensL, lensR, idxL, idxR, wSm, segA, empty, x);
  ent_matvec4<<<dim3(6, 64, 2), 256, 0, stream>>>(x, Wn_ent, Wg_ent, pn, pg);
  ent_reduce<<<24, 256, 0, stream>>>(pn, pg, yn, yg);
  final_kernel<<<1, 256, 0, stream>>>(
      x, yn, yg, bn_ent, bg_ent, Wl_ent, bl_ent, (float*)d_out);
}

// Round 5
// 641.485 us; speedup vs baseline: 1.9003x; 1.0399x over previous
//
#include <hip/hip_runtime.h>
#include <math.h>
#include <stdint.h>

#define DD 768
#define NT 256
#define DE 6144

typedef _Float16 half8 __attribute__((ext_vector_type(8)));
typedef _Float16 half4 __attribute__((ext_vector_type(4)));
typedef short short8 __attribute__((ext_vector_type(8)));
typedef float floatx4 __attribute__((ext_vector_type(4)));

__device__ __forceinline__ void async_ld16(const void* g, void* l) {
  __builtin_amdgcn_global_load_lds(
      (const __attribute__((address_space(1))) unsigned int*)g,
      (__attribute__((address_space(3))) unsigned int*)l, 16, 0, 0);
}

// ---------------------------------------------------------------------------
// Prep A: WT[d][k] = (f16)W[k][d], XOR-swizzled within each 64-f16 chunk:
// 16B-group g of row d lives at group g^(d&7), so lane-contiguous
// global_load_lds lands a bank-balanced image in LDS.
// ---------------------------------------------------------------------------
__global__ __launch_bounds__(256) void transpose_cvt(
    const float* __restrict__ Wn, const float* __restrict__ Wg,
    _Float16* __restrict__ WnT, _Float16* __restrict__ WgT)
{
  const float* W = blockIdx.z ? Wg : Wn;
  _Float16* WT = blockIdx.z ? WgT : WnT;
  __shared__ float tile[32][33];
  const int tx = threadIdx.x & 31, ty = threadIdx.x >> 5;
  const int d0 = blockIdx.x * 32, k0 = blockIdx.y * 32;
  #pragma unroll
  for (int p = 0; p < 4; ++p)
    tile[ty + p*8][tx] = W[(size_t)(k0 + ty + p*8)*DD + d0 + tx];
  __syncthreads();
  #pragma unroll
  for (int p = 0; p < 4; ++p) {
    const int d = d0 + ty + p*8;
    const int k = k0 + tx;
    const int idx = d*DD + (k & ~63) + ((((k >> 3) & 7) ^ (d & 7)) << 3) + (k & 7);
    WT[idx] = (_Float16)tile[tx][ty + p*8];
  }
}

// ---------------------------------------------------------------------------
// Prep B: fp16 copies of the embeddings (A-operand source for score_mfma).
// ---------------------------------------------------------------------------
__global__ __launch_bounds__(256) void cvt_lr(
    const float* __restrict__ L, const float* __restrict__ R,
    _Float16* __restrict__ Lh, _Float16* __restrict__ Rh)
{
  const float* src = blockIdx.y ? R : L;
  _Float16* dst = blockIdx.y ? Rh : Lh;
  const int o = blockIdx.x*1024 + threadIdx.x*4;
  float4 v = *(const float4*)&src[o];
  half4 h; h[0] = (_Float16)v.x; h[1] = (_Float16)v.y;
  h[2] = (_Float16)v.z; h[3] = (_Float16)v.w;
  *(half4*)&dst[o] = h;
}

// ---------------------------------------------------------------------------
// Stage 1: score planes via f16 MFMA. Block = (i, 128 j, 128 d), K=768.
// A (cmp) built from fp16 L/R with packed sub + bitwise abs into swizzled LDS;
// B staged by global_load_lds (async, zero VALU). Epilogue applies the highway
// and Wl contraction; each (dt, d-half-wave) writes its own Sp plane (no
// atomics, no memset). NOTE launch_bounds must stay (256,2): (256,3) spilled
// accumulators in r3 (2.8 GB scratch traffic, 3x slowdown).
// ---------------------------------------------------------------------------
__global__ __launch_bounds__(256, 2) void score_mfma(
    const _Float16* __restrict__ Lh, const _Float16* __restrict__ Rh,
    const _Float16* __restrict__ WnT, const _Float16* __restrict__ WgT,
    const float* __restrict__ bn, const float* __restrict__ bg,
    const float* __restrict__ Wl, float* __restrict__ Sp)
{
  const int jbase = blockIdx.x * 128;
  const int dbase = blockIdx.y * 128;
  const int i     = blockIdx.z;
  const int tid   = threadIdx.x;

  __shared__ _Float16 As [128*64];   // [row][k] swizzled, 16 KB
  __shared__ _Float16 Bns[128*64];
  __shared__ _Float16 Bgs[128*64];

  floatx4 accn[4][4] = {};
  floatx4 accg[4][4] = {};

  const int kg = tid & 7;     // 16B group within 64-f16 chunk
  const int rl = tid >> 3;    // 0..31 base row for A build

  const int lane = tid & 63;
  const int wid  = tid >> 6;
  const int wj = (wid & 1) * 64;
  const int wd = (wid >> 1) * 64;
  const int m = lane & 15;
  const int q = lane >> 4;
  const int gq8 = ((q ^ (m & 7)) << 3);  // swizzled fragment k-offset base

  const int drow = lane >> 3;   // DMA: 8 rows/inst
  const int dseg = lane & 7;

  int aoff[4], boff[4];
  #pragma unroll
  for (int t4 = 0; t4 < 4; ++t4) {
    aoff[t4] = (wj + t4*16 + m) * 64;
    boff[t4] = (wd + t4*16 + m) * 64;
  }

  for (int k0 = 0; k0 < DD; k0 += 64) {
    // ---- B tiles via async global->LDS (swizzled image pre-baked)
    #pragma unroll
    for (int t = 0; t < 4; ++t) {
      const int row = wid*32 + t*8 + drow;
      async_ld16(&WnT[(size_t)(dbase + row)*DD + k0 + dseg*8],
                 &Bns[(wid*32 + t*8)*64]);
      async_ld16(&WgT[(size_t)(dbase + row)*DD + k0 + dseg*8],
                 &Bgs[(wid*32 + t*8)*64]);
    }
    // ---- A tile: |Lh[i,k]-Rh[j,k]| packed fp16, swizzled store
    half8 l8 = *(const half8*)&Lh[i*DD + k0 + kg*8];
    #pragma unroll
    for (int rep = 0; rep < 4; ++rep) {
      const int row = rl + rep*32;
      half8 rv = *(const half8*)&Rh[(size_t)(jbase + row)*DD + k0 + kg*8];
      half8 dv8 = l8 - rv;
      short8 sb; __builtin_memcpy(&sb, &dv8, 16);
      sb &= (short)0x7FFF;
      *(short8*)&As[row*64 + ((kg ^ (row & 7)) << 3)] = sb;
    }
    __syncthreads();
    // ---- MFMA: wave = 64j x 64d, 4x4 16x16 tiles, two matrices
    #pragma unroll
    for (int kk = 0; kk < 64; kk += 32) {
      const int ko = kk ^ gq8;
      half8 af[4], bfn[4], bfg[4];
      #pragma unroll
      for (int t4 = 0; t4 < 4; ++t4) af[t4] = *(const half8*)&As[aoff[t4] + ko];
      #pragma unroll
      for (int t4 = 0; t4 < 4; ++t4) {
        bfn[t4] = *(const half8*)&Bns[boff[t4] + ko];
        bfg[t4] = *(const half8*)&Bgs[boff[t4] + ko];
      }
      #pragma unroll
      for (int tj = 0; tj < 4; ++tj)
        #pragma unroll
        for (int td = 0; td < 4; ++td) {
          accn[tj][td] = __builtin_amdgcn_mfma_f32_16x16x32_f16(
              af[tj], bfn[td], accn[tj][td], 0, 0, 0);
          accg[tj][td] = __builtin_amdgcn_mfma_f32_16x16x32_f16(
              af[tj], bfg[td], accg[tj][td], 0, 0, 0);
        }
    }
    __syncthreads();
  }

  // ---- epilogue: highway + Wl contraction; C layout col=lane&15, row=q*4+r
  float bnv[4], bgv[4], wlv[4], lv[4];
  int dv[4];
  #pragma unroll
  for (int td = 0; td < 4; ++td) {
    const int d = dbase + wd + td*16 + m;
    dv[td] = d; bnv[td] = bn[d]; bgv[td] = bg[d]; wlv[td] = Wl[d];
    lv[td] = (float)Lh[i*DD + d];
  }
  const int jb = jbase + wj;
  const int plane = blockIdx.y * 2 + (wid >> 1);   // 12 planes
  float* Sout = Sp + (size_t)plane * NT * NT + (size_t)i * NT;
  #pragma unroll
  for (int tj = 0; tj < 4; ++tj) {
    #pragma unroll
    for (int r = 0; r < 4; ++r) {
      const int j = jb + tj*16 + q*4 + r;
      float sc = 0.f;
      #pragma unroll
      for (int td = 0; td < 4; ++td) {
        const float nv = accn[tj][td][r] + bnv[td];
        const float gp = accg[tj][td][r] + bgv[td];
        const float g  = 1.f / (1.f + __expf(-gp));
        const float c  = fabsf(lv[td] - (float)Rh[(size_t)j*DD + dv[td]]);
        sc += (fmaxf(nv, 0.f)*g + (1.f - g)*c) * wlv[td];
      }
      sc += __shfl_xor(sc, 1, 16);
      sc += __shfl_xor(sc, 2, 16);
      sc += __shfl_xor(sc, 4, 16);
      sc += __shfl_xor(sc, 8, 16);
      if (m == 0) Sout[j] = sc;
    }
  }
}

// ---------------------------------------------------------------------------
// Stage 2 (fused): blocks 0..511 -> argmax over rows/cols of sum-of-planes S;
// blocks 512/513 -> per-token attribute scores + segment softmax weights.
// ---------------------------------------------------------------------------
__global__ __launch_bounds__(256) void argmax_attr(
    const float* __restrict__ Sp,
    int* __restrict__ idxL, int* __restrict__ idxR,
    const float* __restrict__ Lemb, const float* __restrict__ Remb,
    const float* __restrict__ AEl, const float* __restrict__ AEr,
    const int* __restrict__ lensL, const int* __restrict__ lensR,
    float* __restrict__ wS, int* __restrict__ segA)
{
  const int b = blockIdx.x;
  const int t = threadIdx.x;

  if (b < 2*NT) {
    // ---- argmax path
    const size_t off = (b < NT) ? ((size_t)b*NT + t) : ((size_t)t*NT + (b - NT));
    float v = 0.f;
    #pragma unroll
    for (int p = 0; p < 12; ++p) v += Sp[(size_t)p*NT*NT + off];
    int idx = t;
    #pragma unroll
    for (int mm = 1; mm < 64; mm <<= 1) {
      float ov = __shfl_xor(v, mm, 64);
      int   oi = __shfl_xor(idx, mm, 64);
      if (ov > v || (ov == v && oi < idx)) { v = ov; idx = oi; }
    }
    __shared__ float sv[4]; __shared__ int si[4];
    if ((t & 63) == 0) { sv[t>>6] = v; si[t>>6] = idx; }
    __syncthreads();
    if (t == 0) {
      #pragma unroll
      for (int w = 1; w < 4; ++w)
        if (sv[w] > v || (sv[w] == v && si[w] < idx)) { v = sv[w]; idx = si[w]; }
      if (b < NT) idxL[b] = idx; else idxR[b - NT] = idx;
    }
    return;
  }

  // ---- attr_score path (b = 512 -> left, 513 -> right)
  const int side = b - 2*NT;
  const float* tok = side ? Remb : Lemb;
  const float* AE  = side ? AEr  : AEl;
  const int* lens  = side ? lensR : lensL;
  const int c0 = lens[0], c1 = c0 + lens[1], c2 = c1 + lens[2];
  const int seg = (t < c0) ? 0 : (t < c1) ? 1 : (t < c2) ? 2 : 3;
  float s = 0.f;
  const float4* tr = (const float4*)&tok[(size_t)t*DD];
  const float4* ar = (const float4*)&AE[(size_t)seg*DD];
  for (int k = 0; k < DD/4; ++k) {
    float4 a = tr[k], bb = ar[k];
    s += a.x*bb.x + a.y*bb.y + a.z*bb.z + a.w*bb.w;
  }
  __shared__ float scS[NT]; __shared__ int segS[NT];
  __shared__ float mS[4], zS[4];
  scS[t] = s; segS[t] = seg;
  __syncthreads();
  if (t < 4) {
    float mx = -INFINITY;
    for (int u = 0; u < NT; ++u) if (segS[u] == t) mx = fmaxf(mx, scS[u]);
    mS[t] = mx;
    float z = 0.f;
    for (int u = 0; u < NT; ++u) if (segS[u] == t) z += __expf(scS[u] - mx);
    zS[t] = z;
  }
  __syncthreads();
  wS[side*NT + t] = __expf(s - mS[seg]) / zS[seg];
  segA[side*NT + t] = seg;
}

// ---------------------------------------------------------------------------
// Stage 3: weighted segment reduction of cmp rows, d-parallel (2x12 blocks).
// cmp recomputed in EXACT fp32 from the original embeddings.
// ---------------------------------------------------------------------------
__global__ __launch_bounds__(256) void attr_reduce(
    const float* __restrict__ Lemb, const float* __restrict__ Remb,
    const int* __restrict__ lensL, const int* __restrict__ lensR,
    const int* __restrict__ idxL, const int* __restrict__ idxR,
    const float* __restrict__ wS, const int* __restrict__ segA,
    const float* __restrict__ empty, float* __restrict__ x)
{
  const int side = blockIdx.x;
  const float* tok = side ? Remb : Lemb;
  const float* oth = side ? Lemb : Remb;
  const int* lens  = side ? lensR : lensL;
  const int* idx   = side ? idxR  : idxL;
  const float* w   = wS + side*NT;
  const int* sg    = segA + side*NT;
  float* xo = x + side*4*DD;
  const int t = threadIdx.x;
  const int dl = t & 63, uq = t >> 6;
  const int d = blockIdx.y*64 + dl;
  float a0 = 0.f, a1 = 0.f, a2 = 0.f, a3 = 0.f;
  for (int u = uq*64; u < uq*64 + 64; ++u) {
    const float c = fabsf(tok[(size_t)u*DD + d] - oth[(size_t)idx[u]*DD + d]);
    const float wc = w[u] * c;
    const int s = sg[u];
    a0 += (s == 0) ? wc : 0.f;
    a1 += (s == 1) ? wc : 0.f;
    a2 += (s == 2) ? wc : 0.f;
    a3 += (s == 3) ? wc : 0.f;
  }
  __shared__ float red[4][4][64];
  red[uq][0][dl] = a0; red[uq][1][dl] = a1;
  red[uq][2][dl] = a2; red[uq][3][dl] = a3;
  __syncthreads();
  if (uq == 0) {
    #pragma unroll
    for (int s = 0; s < 4; ++s) {
      float v = red[0][s][dl] + red[1][s][dl] + red[2][s][dl] + red[3][s][dl];
      xo[s*DD + d] = (lens[s] > 0) ? v : empty[d];
    }
  }
}

// ---------------------------------------------------------------------------
// Stage 4a: entity matvecs, float4 streaming, k-split into partials.
// grid (6 col-blocks, 64 k-blocks, 2 matrices) = 768 blocks. HBM-bound.
// ---------------------------------------------------------------------------
__global__ __launch_bounds__(256) void ent_matvec4(
    const float* __restrict__ x,
    const float* __restrict__ Wn, const float* __restrict__ Wg,
    float* __restrict__ pn, float* __restrict__ pg)
{
  const float* W = blockIdx.z ? Wg : Wn;
  float* p = blockIdx.z ? pg : pn;
  __shared__ float xs[96];
  const int db = blockIdx.x;
  const int kb = blockIdx.y;
  const int tid = threadIdx.x;
  if (tid < 96) xs[tid] = x[kb*96 + tid];
  __syncthreads();
  const int col = db*1024 + tid*4;
  float4 a = {0.f,0.f,0.f,0.f};
  const size_t base = (size_t)kb*96*DE + col;
  #pragma unroll 8
  for (int kk = 0; kk < 96; ++kk) {
    const float xv = xs[kk];
    float4 w = *(const float4*)&W[base + (size_t)kk*DE];
    a.x = fmaf(xv, w.x, a.x); a.y = fmaf(xv, w.y, a.y);
    a.z = fmaf(xv, w.z, a.z); a.w = fmaf(xv, w.w, a.w);
  }
  *(float4*)&p[(size_t)kb*DE + col] = a;
}

__global__ __launch_bounds__(256) void ent_reduce(
    const float* __restrict__ pn, const float* __restrict__ pg,
    float* __restrict__ yn, float* __restrict__ yg)
{
  const int o = blockIdx.x*256 + threadIdx.x;
  float sn = 0.f, sg = 0.f;
  for (int kb = 0; kb < 64; ++kb) {
    sn += pn[(size_t)kb*DE + o];
    sg += pg[(size_t)kb*DE + o];
  }
  yn[o] = sn; yg[o] = sg;
}

// ---------------------------------------------------------------------------
// Stage 4b: entity highway + logits + softmax -> out[2].
// ---------------------------------------------------------------------------
__global__ __launch_bounds__(256) void final_kernel(
    const float* __restrict__ x, const float* __restrict__ yn,
    const float* __restrict__ yg, const float* __restrict__ bn,
    const float* __restrict__ bg, const float* __restrict__ Wl,
    const float* __restrict__ bl, float* __restrict__ out)
{
  const int tid = threadIdx.x;
  float a0 = 0.f, a1 = 0.f;
  for (int p = 0; p < DE/256; ++p) {
    int d = p*256 + tid;
    float n  = yn[d] + bn[d];
    float gp = yg[d] + bg[d];
    float h  = fmaxf(n, 0.f);
    float g  = 1.f / (1.f + __expf(-gp));
    float hw = h*g + (1.f - g)*x[d];
    a0 += hw * Wl[d*2 + 0];
    a1 += hw * Wl[d*2 + 1];
  }
  #pragma unroll
  for (int mm = 1; mm < 64; mm <<= 1) {
    a0 += __shfl_xor(a0, mm, 64);
    a1 += __shfl_xor(a1, mm, 64);
  }
  __shared__ float s0[4], s1[4];
  if ((tid & 63) == 0) { s0[tid>>6] = a0; s1[tid>>6] = a1; }
  __syncthreads();
  if (tid == 0) {
    for (int w = 1; w < 4; ++w) { a0 += s0[w]; a1 += s1[w]; }
    float l0 = a0 + bl[0], l1 = a1 + bl[1];
    float m = fmaxf(l0, l1);
    float e0 = __expf(l0 - m), e1 = __expf(l1 - m);
    out[0] = e0 / (e0 + e1);
    out[1] = e1 / (e0 + e1);
  }
}

// ---------------------------------------------------------------------------
extern "C" void kernel_launch(void* const* d_in, const int* in_sizes, int n_in,
                              void* d_out, int out_size, void* d_ws, size_t ws_size,
                              hipStream_t stream) {
  const float* Lemb   = (const float*)d_in[0];
  const float* Remb   = (const float*)d_in[1];
  const float* Wn_tok = (const float*)d_in[2];
  const float* bn_tok = (const float*)d_in[3];
  const float* Wg_tok = (const float*)d_in[4];
  const float* bg_tok = (const float*)d_in[5];
  const float* Wl_tok = (const float*)d_in[6];
  // d_in[7] = b_lin_tok: constant shift, argmax-invariant -> unused
  const float* AEl    = (const float*)d_in[8];
  const float* AEr    = (const float*)d_in[9];
  const float* Wn_ent = (const float*)d_in[10];
  const float* bn_ent = (const float*)d_in[11];
  const float* Wg_ent = (const float*)d_in[12];
  const float* bg_ent = (const float*)d_in[13];
  const float* Wl_ent = (const float*)d_in[14];
  const float* bl_ent = (const float*)d_in[15];
  const float* empty  = (const float*)d_in[16];
  const int*   lensL  = (const int*)d_in[17];
  const int*   lensR  = (const int*)d_in[18];

  char* ws = (char*)d_ws;
  // Sp (12 planes, score stage) overlaps pn/pg (ent stage) -- disjoint in time.
  float* Sp   = (float*)(ws + 0);         // 12*65536 f = 3,145,728 B
  float* pn   = (float*)(ws + 0);         // 64*6144 f = 1,572,864 B
  float* pg   = (float*)(ws + 1572864);   // 64*6144 f
  int*  idxL  = (int*)  (ws + 3145728);   // 256
  int*  idxR  = (int*)  (ws + 3146752);   // 256
  float* x    = (float*)(ws + 3147776);   // 6144 f
  float* yn   = (float*)(ws + 3172352);   // 6144 f
  float* yg   = (float*)(ws + 3196928);   // 6144 f
  float* wSm  = (float*)(ws + 3221504);   // 512 f
  int*  segA  = (int*)  (ws + 3223552);   // 512
  _Float16* WnT = (_Float16*)(ws + 3225600);  // 768*768 f16 (swizzled)
  _Float16* WgT = (_Float16*)(ws + 4405248);  // 768*768 f16 (swizzled)
  _Float16* Lh  = (_Float16*)(ws + 5584896);  // 256*768 f16
  _Float16* Rh  = (_Float16*)(ws + 5978112);  // 256*768 f16

  transpose_cvt<<<dim3(24, 24, 2), 256, 0, stream>>>(Wn_tok, Wg_tok, WnT, WgT);
  cvt_lr<<<dim3(192, 2), 256, 0, stream>>>(Lemb, Remb, Lh, Rh);
  score_mfma<<<dim3(2, 6, NT), 256, 0, stream>>>(
      Lh, Rh, WnT, WgT, bn_tok, bg_tok, Wl_tok, Sp);
  argmax_attr<<<514, 256, 0, stream>>>(
      Sp, idxL, idxR, Lemb, Remb, AEl, AEr, lensL, lensR, wSm, segA);
  attr_reduce<<<dim3(2, 12), 256, 0, stream>>>(
      Lemb, Remb, lensL, lensR, idxL, idxR, wSm, segA, empty, x);
  ent_matvec4<<<dim3(6, 64, 2), 256, 0, stream>>>(x, Wn_ent, Wg_ent, pn, pg);
  ent_reduce<<<24, 256, 0, stream>>>(pn, pg, yn, yg);
  final_kernel<<<1, 256, 0, stream>>>(
      x, yn, yg, bn_ent, bg_ent, Wl_ent, bl_ent, (float*)d_out);
}